// Round 3
// baseline (11897.185 us; speedup 1.0000x reference)
//
#include <hip/hip_runtime.h>

// ---- problem constants ----
namespace {
constexpr int nT = 64;
constexpr int nK = 7;
constexpr long N_PSI = 1123776;
constexpr long SZ_WHH = 1048576;       // psi region 0: (1024,1024)
constexpr long REST_SZ = 75200;        // per-sample remaining psi elems
constexpr long R_BH = 0;               // (1024,)
constexpr long R_WIH = 1024;           // (8,1024)
constexpr long R_C = 9216;             // (1024,64)
constexpr long R_D = 74752;            // (8,56)
constexpr int NCH = 16;                // h-chunks per step
constexpr int CHR = 64;                // rows per chunk (1024/16)
constexpr int NBLK = 512;              // persistent grid (16 chunks x 32 sample-pairs)
constexpr long PHALF = (long)NCH * 64 * 1024;  // one partial buffer (floats)
}

typedef __attribute__((ext_vector_type(4))) unsigned short us4;

__device__ __forceinline__ float b2f(unsigned short u) {
  return __uint_as_float(((unsigned int)u) << 16);
}
__device__ __forceinline__ unsigned short f2b(float f) {
  unsigned int u = __float_as_uint(f);
  return (unsigned short)((u + 0x7fffu + ((u >> 16) & 1u)) >> 16);
}
__device__ __forceinline__ float sigm(float x) { return 1.f / (1.f + __expf(-x)); }

// monotonic grid barrier: every block arrives exactly once per episode; no reset.
__device__ __forceinline__ void gbar(unsigned* cnt) {
  __syncthreads();
  if (threadIdx.x == 0) {
    unsigned old = __hip_atomic_fetch_add(cnt, 1u, __ATOMIC_ACQ_REL, __HIP_MEMORY_SCOPE_AGENT);
    unsigned target = (old / NBLK + 1u) * NBLK;
    while (__hip_atomic_load(cnt, __ATOMIC_ACQUIRE, __HIP_MEMORY_SCOPE_AGENT) < target)
      __builtin_amdgcn_s_sleep(2);
  }
  __syncthreads();
}

// ---------- one-time: transpose (rows,cols) fp32 -> bf16 out[c*rows + r] ----------
__global__ void transpose_bf16_k(const float* __restrict__ in, unsigned short* __restrict__ out,
                                 int rows, int cols) {
  __shared__ float tile[32][33];
  int x = blockIdx.x * 32 + threadIdx.x;
  int y = blockIdx.y * 32 + threadIdx.y;
  #pragma unroll
  for (int i = 0; i < 32; i += 8)
    if ((y + i) < rows && x < cols) tile[threadIdx.y + i][threadIdx.x] = in[(long)(y + i) * cols + x];
  __syncthreads();
  x = blockIdx.y * 32 + threadIdx.x;
  y = blockIdx.x * 32 + threadIdx.y;
  #pragma unroll
  for (int i = 0; i < 32; i += 8)
    if ((y + i) < cols && x < rows) out[(long)(y + i) * rows + x] = f2b(tile[threadIdx.x][threadIdx.y + i]);
}

__global__ void cvt_bf16_k(const float* __restrict__ in, unsigned short* __restrict__ out, long n) {
  long i = (long)blockIdx.x * 256 + threadIdx.x;
  if (i < n) out[i] = f2b(in[i]);
}

// ---------- bulk precompute: encoder gx (includes bih) ----------
__global__ __launch_bounds__(256) void enc_gx_k(const float* __restrict__ outputs,
                                                const unsigned short* __restrict__ WtWihB,
                                                const float* __restrict__ bih,
                                                unsigned short* __restrict__ gxE) {
  int g = blockIdx.x * 256 + threadIdx.x;       // 0..3071
  int b = blockIdx.y & 63, t = blockIdx.y >> 6;
  __shared__ float xs[64];
  if (threadIdx.x < 64) xs[threadIdx.x] = outputs[((long)b * nT + t) * 64 + threadIdx.x];
  __syncthreads();
  float acc = bih[g];
  #pragma unroll 8
  for (int i = 0; i < 64; ++i) acc += xs[i] * b2f(WtWihB[(long)i * 3072 + g]);
  gxE[((long)t * 64 + b) * 3072 + g] = f2b(acc);
}

// ---------- bulk precompute: decoder gx (includes gbias) ----------
__global__ __launch_bounds__(256) void dec_gx_k(const float* __restrict__ inputs,
                                                const float* __restrict__ gWih,
                                                const float* __restrict__ gbias,
                                                unsigned short* __restrict__ gxD) {
  int k = blockIdx.x * 256 + threadIdx.x;       // 0..2047
  int b = blockIdx.y & 63, t = blockIdx.y >> 6;
  __shared__ float xs[8];
  if (threadIdx.x < 8) xs[threadIdx.x] = inputs[((long)b * nT + t) * 8 + threadIdx.x];
  __syncthreads();
  float acc = gbias[k];
  #pragma unroll
  for (int i = 0; i < 8; ++i) acc += xs[i] * gWih[i * 2048 + k];
  gxD[((long)t * 64 + b) * 2048 + k] = f2b(acc);
}

// ---------- bulk precompute: x @ Wih_b per sample ----------
__global__ __launch_bounds__(256) void xW_k(const float* __restrict__ inputs,
                                            const float* __restrict__ Rest,
                                            unsigned short* __restrict__ xWb) {
  int k = blockIdx.x * 256 + threadIdx.x;       // 0..1023
  int b = blockIdx.y & 63, t = blockIdx.y >> 6;
  __shared__ float xs[8];
  if (threadIdx.x < 8) xs[threadIdx.x] = inputs[((long)b * nT + t) * 8 + threadIdx.x];
  __syncthreads();
  const float* RB = Rest + (long)b * REST_SZ + R_WIH;
  float acc = 0.f;
  #pragma unroll
  for (int i = 0; i < 8; ++i) acc += xs[i] * RB[(long)i * 1024 + k];
  xWb[((long)t * 64 + b) * 1024 + k] = f2b(acc);
}

// ---------- persistent encoder recurrence ----------
__global__ __launch_bounds__(256, 2) void enc_persist_k(
    const unsigned short* __restrict__ W,       // [1024][3072] bf16 enc_Whh^T
    const unsigned short* __restrict__ gxE,     // [T][B][3072] bf16 (incl bih)
    const float* __restrict__ bhh,
    float* __restrict__ hEnc,                   // [B][1024] final h
    float* __restrict__ pR0, float* __restrict__ pZ0, float* __restrict__ pN0,
    unsigned* __restrict__ bar) {
  int c = blockIdx.x & (NCH - 1);
  int sp = blockIdx.x >> 4;
  int b0 = sp * 2, b1 = b0 + 1;
  int e0 = threadIdx.x * 4;
  __shared__ float h0s[CHR], h1s[CHR];
  if (threadIdx.x < CHR) h0s[threadIdx.x] = 0.f;
  else if (threadIdx.x < 2 * CHR) h1s[threadIdx.x - CHR] = 0.f;
  __syncthreads();

  for (int t = 0; t < nT; ++t) {
    long po = (t & 1) * PHALF;
    float* pR = pR0 + po; float* pZ = pZ0 + po; float* pN = pN0 + po;
    if (t > 0) {
      float ar0[4] = {}, az0[4] = {}, an0[4] = {}, ar1[4] = {}, az1[4] = {}, an1[4] = {};
      const unsigned short* Wb = W + (long)(c * CHR) * 3072 + e0;
      #pragma unroll 4
      for (int j = 0; j < CHR; ++j) {
        us4 wr = *(const us4*)(Wb + (long)j * 3072);
        us4 wz = *(const us4*)(Wb + (long)j * 3072 + 1024);
        us4 wn = *(const us4*)(Wb + (long)j * 3072 + 2048);
        float hv0 = h0s[j], hv1 = h1s[j];
        #pragma unroll
        for (int q = 0; q < 4; ++q) {
          float fr = b2f(wr[q]), fz = b2f(wz[q]), fn = b2f(wn[q]);
          ar0[q] += hv0 * fr; az0[q] += hv0 * fz; an0[q] += hv0 * fn;
          ar1[q] += hv1 * fr; az1[q] += hv1 * fz; an1[q] += hv1 * fn;
        }
      }
      long i0 = ((long)c * 64 + b0) * 1024 + e0;
      long i1 = i0 + 1024;
      *(float4*)(pR + i0) = make_float4(ar0[0], ar0[1], ar0[2], ar0[3]);
      *(float4*)(pZ + i0) = make_float4(az0[0], az0[1], az0[2], az0[3]);
      *(float4*)(pN + i0) = make_float4(an0[0], an0[1], an0[2], an0[3]);
      *(float4*)(pR + i1) = make_float4(ar1[0], ar1[1], ar1[2], ar1[3]);
      *(float4*)(pZ + i1) = make_float4(az1[0], az1[1], az1[2], az1[3]);
      *(float4*)(pN + i1) = make_float4(an1[0], an1[1], an1[2], an1[3]);
    }
    gbar(bar);
    int v = threadIdx.x;
    if (v < 2 * CHR) {
      int hi = v >> 6;
      int bb = hi ? b1 : b0;
      int e = c * CHR + (v & 63);
      float sr = 0.f, sz = 0.f, sn = 0.f;
      if (t > 0) {
        #pragma unroll
        for (int cc = 0; cc < NCH; ++cc) {
          long base = ((long)cc * 64 + bb) * 1024 + e;
          sr += pR[base]; sz += pZ[base]; sn += pN[base];
        }
      }
      long gb = ((long)t * 64 + bb) * 3072;
      float xr = b2f(gxE[gb + e]), xz = b2f(gxE[gb + 1024 + e]), xn = b2f(gxE[gb + 2048 + e]);
      float hr = sr + bhh[e], hz = sz + bhh[1024 + e], hn = sn + bhh[2048 + e];
      float r = sigm(xr + hr);
      float z = sigm(xz + hz);
      float n = tanhf(xn + r * hn);
      float hold = hi ? h1s[v & 63] : h0s[v & 63];
      float hnew = (1.f - z) * n + z * hold;
      if (hi) h1s[v & 63] = hnew; else h0s[v & 63] = hnew;
      if (t == nT - 1) hEnc[(long)bb * 1024 + e] = hnew;
    }
    __syncthreads();
  }
}

// ---------- latent ----------
__global__ void latent_k(const float* __restrict__ h_enc,
                         const float* __restrict__ to_mu, const float* __restrict__ to_lsig,
                         const float* __restrict__ lsig_bias, const float* __restrict__ eps,
                         float* __restrict__ out_mu, float* __restrict__ out_lsig,
                         float* __restrict__ zlat) {
  int b = blockIdx.x;
  __shared__ float hs[1024];
  for (int i = threadIdx.x; i < 1024; i += blockDim.x) hs[i] = h_enc[b * 1024 + i];
  __syncthreads();
  int k = threadIdx.x;
  if (k < nK) {
    float am = 0.f, as = 0.f;
    for (int h = 0; h < 1024; ++h) { float hv = hs[h]; am += hv * to_mu[h * nK + k]; as += hv * to_lsig[h * nK + k]; }
    float ls = as + lsig_bias[k];
    out_mu[b * nK + k] = am;
    out_lsig[b * nK + k] = ls;
    zlat[b * nK + k] = am + eps[b * nK + k] * __expf(ls);
  }
}

// ---------- hypernet layers 1-2 ----------
__global__ __launch_bounds__(256) void hyper_k(const float* __restrict__ zlat,
                                               const float* __restrict__ W1, const float* __restrict__ b1,
                                               const float* __restrict__ W2, const float* __restrict__ b2,
                                               float* __restrict__ a2out) {
  int b = blockIdx.x;
  __shared__ float a1[1024];
  __shared__ float zv[nK];
  if (threadIdx.x < nK) zv[threadIdx.x] = zlat[b * nK + threadIdx.x];
  __syncthreads();
  for (int j = threadIdx.x; j < 1024; j += 256) {
    float acc = b1[j];
    #pragma unroll
    for (int i = 0; i < nK; ++i) acc += zv[i] * W1[i * 1024 + j];
    a1[j] = tanhf(acc);
  }
  __syncthreads();
  int l = threadIdx.x >> 3;
  int s = threadIdx.x & 7;
  if (l < 30) {
    float acc = 0.f;
    for (int j = s; j < 1024; j += 8) acc += a1[j] * W2[j * 30 + l];
    acc += __shfl_xor(acc, 4);
    acc += __shfl_xor(acc, 2);
    acc += __shfl_xor(acc, 1);
    if (s == 0) a2out[b * 30 + l] = acc + b2[l];
  }
}

// ---------- psi materialization ----------
__global__ __launch_bounds__(256) void psi_k(const float* __restrict__ a2,
                                             const float* __restrict__ W3, const float* __restrict__ b3,
                                             unsigned short* __restrict__ WhhB, float* __restrict__ Rest) {
  __shared__ float sa[64 * 30];
  for (int i = threadIdx.x; i < 64 * 30; i += 256) sa[i] = a2[i];
  long n = (long)blockIdx.x * 256 + threadIdx.x;
  __syncthreads();
  if (n >= N_PSI) return;
  float w[30];
  #pragma unroll
  for (int l = 0; l < 30; ++l) w[l] = W3[(long)l * N_PSI + n];
  float bb = b3[n];
  bool isWhh = (n < SZ_WHH);
  for (int b = 0; b < 64; ++b) {
    float acc = bb;
    const float* ab = &sa[b * 30];
    #pragma unroll
    for (int l = 0; l < 30; ++l) acc += ab[l] * w[l];
    if (isWhh) WhhB[(long)b * SZ_WHH + n] = f2b(acc);
    else       Rest[(long)b * REST_SZ + (n - SZ_WHH)] = acc;
  }
}

// ---------- persistent decoder recurrence ----------
__global__ __launch_bounds__(256, 2) void dec_persist_k(
    const unsigned short* __restrict__ WhhB,   // [B][1024][1024] bf16
    const unsigned short* __restrict__ gWhhB,  // [1024][2048] bf16
    const unsigned short* __restrict__ gxD,    // [T][B][2048] bf16 (incl gbias)
    const unsigned short* __restrict__ xWb,    // [T][B][1024] bf16
    const float* __restrict__ Rest,
    float* __restrict__ decS,                  // [B][T][1024]
    float* __restrict__ pZ0, float* __restrict__ pR0, float* __restrict__ pW0,
    unsigned* __restrict__ bar) {
  int c = blockIdx.x & (NCH - 1);
  int sp = blockIdx.x >> 4;
  int b0 = sp * 2, b1 = b0 + 1;
  int k0 = threadIdx.x * 4;
  __shared__ float h0s[CHR], h1s[CHR];
  if (threadIdx.x < CHR) h0s[threadIdx.x] = 0.f;
  else if (threadIdx.x < 2 * CHR) h1s[threadIdx.x - CHR] = 0.f;
  __syncthreads();

  for (int t = 0; t < nT; ++t) {
    long po = (t & 1) * PHALF;
    float* pZ = pZ0 + po; float* pR = pR0 + po; float* pW = pW0 + po;
    if (t > 0) {
      float az0[4] = {}, ar0[4] = {}, aw0[4] = {}, az1[4] = {}, ar1[4] = {}, aw1[4] = {};
      const unsigned short* G = gWhhB + (long)(c * CHR) * 2048 + k0;
      const unsigned short* W0 = WhhB + (long)b0 * SZ_WHH + (long)(c * CHR) * 1024 + k0;
      const unsigned short* W1p = WhhB + (long)b1 * SZ_WHH + (long)(c * CHR) * 1024 + k0;
      #pragma unroll 4
      for (int j = 0; j < CHR; ++j) {
        us4 wz = *(const us4*)(G + (long)j * 2048);
        us4 wr = *(const us4*)(G + (long)j * 2048 + 1024);
        us4 w0 = *(const us4*)(W0 + (long)j * 1024);
        us4 w1 = *(const us4*)(W1p + (long)j * 1024);
        float hv0 = h0s[j], hv1 = h1s[j];
        #pragma unroll
        for (int q = 0; q < 4; ++q) {
          float fz = b2f(wz[q]), fr = b2f(wr[q]), f0 = b2f(w0[q]), f1 = b2f(w1[q]);
          az0[q] += hv0 * fz; ar0[q] += hv0 * fr; aw0[q] += hv0 * f0;
          az1[q] += hv1 * fz; ar1[q] += hv1 * fr; aw1[q] += hv1 * f1;
        }
      }
      long i0 = ((long)c * 64 + b0) * 1024 + k0;
      long i1 = i0 + 1024;
      *(float4*)(pZ + i0) = make_float4(az0[0], az0[1], az0[2], az0[3]);
      *(float4*)(pR + i0) = make_float4(ar0[0], ar0[1], ar0[2], ar0[3]);
      *(float4*)(pW + i0) = make_float4(aw0[0], aw0[1], aw0[2], aw0[3]);
      *(float4*)(pZ + i1) = make_float4(az1[0], az1[1], az1[2], az1[3]);
      *(float4*)(pR + i1) = make_float4(ar1[0], ar1[1], ar1[2], ar1[3]);
      *(float4*)(pW + i1) = make_float4(aw1[0], aw1[1], aw1[2], aw1[3]);
    }
    gbar(bar);
    int v = threadIdx.x;
    if (v < 2 * CHR) {
      int hi = v >> 6;
      int bb = hi ? b1 : b0;
      int k = c * CHR + (v & 63);
      float sz = 0.f, sr = 0.f, sw = 0.f;
      if (t > 0) {
        #pragma unroll
        for (int cc = 0; cc < NCH; ++cc) {
          long base = ((long)cc * 64 + bb) * 1024 + k;
          sz += pZ[base]; sr += pR[base]; sw += pW[base];
        }
      }
      long gb = ((long)t * 64 + bb) * 2048;
      float gz = b2f(gxD[gb + k]), gr = b2f(gxD[gb + 1024 + k]);
      float z = sigm(gz + sz);
      float r = sigm(gr + sr);
      float hW = sw + Rest[(long)bb * REST_SZ + R_BH + k];
      float xw = b2f(xWb[((long)t * 64 + bb) * 1024 + k]);
      float eta = tanhf(xw + r * tanhf(hW));
      float hold = hi ? h1s[v & 63] : h0s[v & 63];
      float hnew = z * hold + (1.f - z) * eta;
      if (hi) h1s[v & 63] = hnew; else h0s[v & 63] = hnew;
      decS[((long)bb * nT + t) * 1024 + k] = hnew;
    }
    __syncthreads();
  }
}

// ---------- readout ----------
__global__ __launch_bounds__(256) void readout_k(
    const float* __restrict__ dec_seq, const float* __restrict__ inputs,
    const float* __restrict__ Rest, float* __restrict__ yhats) {
  int bt = blockIdx.x; int b = bt >> 6;
  __shared__ float ss[1024];
  __shared__ float part[4][64];
  for (int i = threadIdx.x; i < 1024; i += 256) ss[i] = dec_seq[(long)bt * 1024 + i];
  __syncthreads();
  int w = threadIdx.x >> 6, m = threadIdx.x & 63;
  const float* C = Rest + (long)b * REST_SZ + R_C;
  float acc = 0.f;
  #pragma unroll 4
  for (int h = w * 256; h < w * 256 + 256; ++h) acc += ss[h] * C[(long)h * 64 + m];
  part[w][m] = acc;
  __syncthreads();
  if (threadIdx.x < 64) {
    float a = part[0][m] + part[1][m] + part[2][m] + part[3][m];
    if (m < 8) {
      a += inputs[(long)bt * 8 + m];
    } else {
      const float* D = Rest + (long)b * REST_SZ + R_D;
      #pragma unroll
      for (int i = 0; i < 8; ++i) a += inputs[(long)bt * 8 + i] * D[i * 56 + (m - 8)];
    }
    yhats[(long)bt * 64 + m] = a;
  }
}

__global__ void copy_states_k(const float* __restrict__ dec_seq, float* __restrict__ states) {
  int i = blockIdx.x * 256 + threadIdx.x;
  int b = i >> 10, h = i & 1023;
  states[i] = dec_seq[((long)b * nT + (nT - 1)) * 1024 + h];
}

extern "C" void kernel_launch(void* const* d_in, const int* in_sizes, int n_in,
                              void* d_out, int out_size, void* d_ws, size_t ws_size,
                              hipStream_t stream) {
  const float* inputs  = (const float*)d_in[0];
  const float* outputs = (const float*)d_in[1];
  const float* eps     = (const float*)d_in[2];
  const float* enc_Wih = (const float*)d_in[3];
  const float* enc_Whh = (const float*)d_in[4];
  const float* enc_bih = (const float*)d_in[5];
  const float* enc_bhh = (const float*)d_in[6];
  const float* to_mu   = (const float*)d_in[7];
  const float* to_lsig = (const float*)d_in[8];
  const float* lsig_b  = (const float*)d_in[9];
  const float* W1 = (const float*)d_in[10];
  const float* b1 = (const float*)d_in[11];
  const float* W2 = (const float*)d_in[12];
  const float* b2 = (const float*)d_in[13];
  const float* W3 = (const float*)d_in[14];
  const float* b3 = (const float*)d_in[15];
  const float* gWih  = (const float*)d_in[16];
  const float* gWhh  = (const float*)d_in[17];
  const float* gbias = (const float*)d_in[18];

  char* ws = (char*)d_ws;
  size_t off = 0;
  auto alloc = [&](size_t bytes) { size_t o = off; off = (off + bytes + 255) & ~(size_t)255; return o; };
  size_t oWhhB   = alloc(64ull * SZ_WHH * 2);        // bf16 per-sample Whh
  size_t oRest   = alloc(64ull * REST_SZ * 4);       // fp32 psi remainder
  size_t ogWhhB  = alloc(1024ull * 2048 * 2);        // bf16 gru_Whh
  size_t oWtWhhB = alloc(1024ull * 3072 * 2);        // bf16 enc_Whh^T
  size_t oWtWihB = alloc(64ull * 3072 * 2);          // bf16 enc_Wih^T
  size_t ogxE    = alloc(64ull * 64 * 3072 * 2);     // bf16 encoder gx (incl bih)
  size_t ogxD    = alloc(64ull * 64 * 2048 * 2);     // bf16 decoder gx (incl gbias)
  size_t oxWb    = alloc(64ull * 64 * 1024 * 2);     // bf16 x@Wih_b
  size_t opA     = alloc((size_t)2 * PHALF * 4);     // double-buffered partials
  size_t opB     = alloc((size_t)2 * PHALF * 4);
  size_t opC     = alloc((size_t)2 * PHALF * 4);
  size_t ohA     = alloc(64ull * 1024 * 4);
  size_t oDec    = alloc(64ull * 64 * 1024 * 4);
  size_t oZ      = alloc(64 * nK * 4);
  size_t oA2     = alloc(64 * 30 * 4);
  size_t oBar    = alloc(2 * sizeof(unsigned));
  (void)ws_size; (void)in_sizes; (void)n_in; (void)out_size;

  unsigned short* WhhB   = (unsigned short*)(ws + oWhhB);
  float*          Rest   = (float*)(ws + oRest);
  unsigned short* gWhhB  = (unsigned short*)(ws + ogWhhB);
  unsigned short* WtWhhB = (unsigned short*)(ws + oWtWhhB);
  unsigned short* WtWihB = (unsigned short*)(ws + oWtWihB);
  unsigned short* gxE    = (unsigned short*)(ws + ogxE);
  unsigned short* gxD    = (unsigned short*)(ws + ogxD);
  unsigned short* xWb    = (unsigned short*)(ws + oxWb);
  float* pA   = (float*)(ws + opA);
  float* pB   = (float*)(ws + opB);
  float* pC   = (float*)(ws + opC);
  float* hA   = (float*)(ws + ohA);
  float* decS = (float*)(ws + oDec);
  float* zlat = (float*)(ws + oZ);
  float* a2   = (float*)(ws + oA2);
  unsigned* bar = (unsigned*)(ws + oBar);

  float* out    = (float*)d_out;
  float* out_yh = out;                 // 262144
  float* out_mu = out + 262144;        // 448
  float* out_ls = out + 262144 + 448;  // 448
  float* out_st = out + 262144 + 896;  // 65536

  // 0) reset barriers
  hipMemsetAsync(bar, 0, 2 * sizeof(unsigned), stream);

  // 1) weight preprocessing (bf16)
  transpose_bf16_k<<<dim3(32, 96), dim3(32, 8), 0, stream>>>(enc_Whh, WtWhhB, 3072, 1024);
  transpose_bf16_k<<<dim3(2, 96),  dim3(32, 8), 0, stream>>>(enc_Wih, WtWihB, 3072, 64);
  cvt_bf16_k<<<(int)((1024ull * 2048 + 255) / 256), 256, 0, stream>>>(gWhh, gWhhB, 1024 * 2048);

  // 2) bulk encoder gx
  enc_gx_k<<<dim3(12, 4096), 256, 0, stream>>>(outputs, WtWihB, enc_bih, gxE);

  // 3) encoder recurrence (persistent)
  enc_persist_k<<<NBLK, 256, 0, stream>>>(WtWhhB, gxE, enc_bhh, hA, pA, pB, pC, bar);

  // 4) latent + hypernet + psi
  latent_k<<<64, 64, 0, stream>>>(hA, to_mu, to_lsig, lsig_b, eps, out_mu, out_ls, zlat);
  hyper_k<<<64, 256, 0, stream>>>(zlat, W1, b1, W2, b2, a2);
  psi_k<<<(int)((N_PSI + 255) / 256), 256, 0, stream>>>(a2, W3, b3, WhhB, Rest);

  // 5) bulk decoder gx and x@Wih_b
  dec_gx_k<<<dim3(8, 4096), 256, 0, stream>>>(inputs, gWih, gbias, gxD);
  xW_k<<<dim3(4, 4096), 256, 0, stream>>>(inputs, Rest, xWb);

  // 6) decoder recurrence (persistent)
  dec_persist_k<<<NBLK, 256, 0, stream>>>(WhhB, gWhhB, gxD, xWb, Rest, decS, pA, pB, pC, bar + 1);

  // 7) readout + states
  readout_k<<<4096, 256, 0, stream>>>(decS, inputs, Rest, out_yh);
  copy_states_k<<<256, 256, 0, stream>>>(decS, out_st);
}

// Round 4
// 3184.627 us; speedup vs baseline: 3.7358x; 3.7358x over previous
//
#include <hip/hip_runtime.h>

// ---- problem constants ----
namespace {
constexpr int nT = 64;
constexpr int nK = 7;
constexpr long N_PSI = 1123776;
constexpr long SZ_WHH = 1048576;       // psi region 0: (1024,1024)
constexpr long REST_SZ = 75200;        // per-sample remaining psi elems
constexpr long R_BH = 0;               // (1024,)
constexpr long R_WIH = 1024;           // (8,1024)
constexpr long R_C = 9216;             // (1024,64)
constexpr long R_D = 74752;            // (8,56)
constexpr int NCH = 16;                // h-chunks per step
constexpr int CHR = 64;                // rows per chunk (1024/16)
constexpr long PHALF = (long)NCH * 64 * 1024;  // one partial buffer (floats)
}

typedef __attribute__((ext_vector_type(4))) unsigned short us4;

__device__ __forceinline__ float b2f(unsigned short u) {
  return __uint_as_float(((unsigned int)u) << 16);
}
__device__ __forceinline__ unsigned short f2b(float f) {
  unsigned int u = __float_as_uint(f);
  return (unsigned short)((u + 0x7fffu + ((u >> 16) & 1u)) >> 16);
}
__device__ __forceinline__ float sigm(float x) { return 1.f / (1.f + __expf(-x)); }

// ---------- one-time: transpose (rows,cols) fp32 -> bf16 out[c*rows + r] ----------
__global__ void transpose_bf16_k(const float* __restrict__ in, unsigned short* __restrict__ out,
                                 int rows, int cols) {
  __shared__ float tile[32][33];
  int x = blockIdx.x * 32 + threadIdx.x;
  int y = blockIdx.y * 32 + threadIdx.y;
  #pragma unroll
  for (int i = 0; i < 32; i += 8)
    if ((y + i) < rows && x < cols) tile[threadIdx.y + i][threadIdx.x] = in[(long)(y + i) * cols + x];
  __syncthreads();
  x = blockIdx.y * 32 + threadIdx.x;
  y = blockIdx.x * 32 + threadIdx.y;
  #pragma unroll
  for (int i = 0; i < 32; i += 8)
    if ((y + i) < cols && x < rows) out[(long)(y + i) * rows + x] = f2b(tile[threadIdx.x][threadIdx.y + i]);
}

__global__ void cvt_bf16_k(const float* __restrict__ in, unsigned short* __restrict__ out, long n) {
  long i = (long)blockIdx.x * 256 + threadIdx.x;
  if (i < n) out[i] = f2b(in[i]);
}

// ---------- bulk: encoder gx (weight stripe staged in LDS, 64 bt per block) ----------
__global__ __launch_bounds__(256) void enc_gx_k(const float* __restrict__ outputs,
                                                const unsigned short* __restrict__ WtWihB,
                                                const float* __restrict__ bih,
                                                unsigned short* __restrict__ gxE) {
  int g0 = blockIdx.x * 256;           // 12 g-slices of 256 (3072)
  int btg = blockIdx.y;                // 64 groups of 64 bt items
  __shared__ unsigned short ws[64 * 256];   // 32 KB
  __shared__ float xs[64][64];              // 16 KB
  for (int i = threadIdx.x; i < 64 * 256; i += 256)
    ws[i] = WtWihB[(long)(i >> 8) * 3072 + g0 + (i & 255)];
  for (int i = threadIdx.x; i < 64 * 64; i += 256) {
    int idx = btg * 64 + (i >> 6);     // tb index: t = idx>>6, b = idx&63
    int t = idx >> 6, b = idx & 63;
    xs[i >> 6][i & 63] = outputs[((long)b * nT + t) * 64 + (i & 63)];
  }
  __syncthreads();
  float bihv = bih[g0 + threadIdx.x];
  for (int j = 0; j < 64; ++j) {
    int idx = btg * 64 + j;
    float acc = bihv;
    #pragma unroll 8
    for (int i = 0; i < 64; ++i) acc += xs[j][i] * b2f(ws[i * 256 + threadIdx.x]);
    gxE[(long)idx * 3072 + g0 + threadIdx.x] = f2b(acc);
  }
}

// ---------- bulk: decoder gx ----------
__global__ __launch_bounds__(256) void dec_gx_k(const float* __restrict__ inputs,
                                                const float* __restrict__ gWih,
                                                const float* __restrict__ gbias,
                                                unsigned short* __restrict__ gxD) {
  int g0 = blockIdx.x * 256;           // 8 slices of 256 (2048)
  int btg = blockIdx.y;
  __shared__ float ws[8][256];
  __shared__ float xs[64][8];
  for (int i = threadIdx.x; i < 8 * 256; i += 256)
    ws[i >> 8][i & 255] = gWih[(long)(i >> 8) * 2048 + g0 + (i & 255)];
  for (int i = threadIdx.x; i < 64 * 8; i += 256) {
    int idx = btg * 64 + (i >> 3);
    int t = idx >> 6, b = idx & 63;
    xs[i >> 3][i & 7] = inputs[((long)b * nT + t) * 8 + (i & 7)];
  }
  __syncthreads();
  float bv = gbias[g0 + threadIdx.x];
  for (int j = 0; j < 64; ++j) {
    int idx = btg * 64 + j;
    float acc = bv;
    #pragma unroll
    for (int i = 0; i < 8; ++i) acc += xs[j][i] * ws[i][threadIdx.x];
    gxD[(long)idx * 2048 + g0 + threadIdx.x] = f2b(acc);
  }
}

// ---------- bulk: x @ Wih_b per sample ----------
__global__ __launch_bounds__(256) void xW_k(const float* __restrict__ inputs,
                                            const float* __restrict__ Rest,
                                            unsigned short* __restrict__ xWb) {
  int k0 = blockIdx.x * 256;           // 4 slices of 256 (1024)
  int b = blockIdx.y;                  // sample
  __shared__ float ws[8][256];
  __shared__ float xs[64][8];
  const float* RB = Rest + (long)b * REST_SZ + R_WIH;
  for (int i = threadIdx.x; i < 8 * 256; i += 256)
    ws[i >> 8][i & 255] = RB[(long)(i >> 8) * 1024 + k0 + (i & 255)];
  for (int i = threadIdx.x; i < 64 * 8; i += 256)
    xs[i >> 3][i & 7] = inputs[((long)b * nT + (i >> 3)) * 8 + (i & 7)];
  __syncthreads();
  for (int t = 0; t < 64; ++t) {
    float acc = 0.f;
    #pragma unroll
    for (int i = 0; i < 8; ++i) acc += xs[t][i] * ws[i][threadIdx.x];
    xWb[((long)t * 64 + b) * 1024 + k0 + threadIdx.x] = f2b(acc);
  }
}

// ---------- encoder fused step: reduce(t) + gates -> h in LDS -> partials(t+1) ----------
__global__ __launch_bounds__(256) void enc_step_k(
    const unsigned short* __restrict__ W,       // [1024][3072] bf16 enc_Whh^T
    const unsigned short* __restrict__ gxE,     // [T][B][3072] bf16 (incl bih)
    const float* __restrict__ bhh,
    float* __restrict__ hEnc,                   // [B][1024] final h
    const float* __restrict__ pRr, const float* __restrict__ pZr, const float* __restrict__ pNr,
    float* __restrict__ pRw, float* __restrict__ pZw, float* __restrict__ pNw,
    int t) {
  int c = blockIdx.x & (NCH - 1);
  int sp = blockIdx.x >> 4;
  int b0 = sp * 2, b1 = b0 + 1;
  __shared__ float h0s[CHR], h1s[CHR];

  // phase A: reduce previous partials + gates -> h(t) rows of chunk c
  int v = threadIdx.x;
  if (v < 2 * CHR) {
    int hi = v >> 6;
    int bb = hi ? b1 : b0;
    int e = c * CHR + (v & 63);
    float sr = 0.f, sz = 0.f, sn = 0.f;
    if (t > 0) {
      #pragma unroll
      for (int cc = 0; cc < NCH; ++cc) {
        long base = ((long)cc * 64 + bb) * 1024 + e;
        sr += pRr[base]; sz += pZr[base]; sn += pNr[base];
      }
    }
    long gb = ((long)t * 64 + bb) * 3072;
    float xr = b2f(gxE[gb + e]), xz = b2f(gxE[gb + 1024 + e]), xn = b2f(gxE[gb + 2048 + e]);
    float hr = sr + bhh[e], hz = sz + bhh[1024 + e], hn = sn + bhh[2048 + e];
    float r = sigm(xr + hr);
    float z = sigm(xz + hz);
    float n = tanhf(xn + r * hn);
    // previous h for this row lives only in the leak term z*h_old; reconstruct:
    // h_old must be read from partial-producing LDS of previous step — not available.
    // Instead we carry h_old via global: see hPrev below.
    float hold = 0.f;
    if (t > 0) hold = hEnc[(long)bb * 1024 + e];
    float hnew = (1.f - z) * n + z * hold;
    hEnc[(long)bb * 1024 + e] = hnew;
    if (hi) h1s[v & 63] = hnew; else h0s[v & 63] = hnew;
  }
  __syncthreads();

  // phase B: partials for t+1
  if (t < nT - 1) {
    int e0 = threadIdx.x * 4;
    float ar0[4] = {}, az0[4] = {}, an0[4] = {}, ar1[4] = {}, az1[4] = {}, an1[4] = {};
    const unsigned short* Wb = W + (long)(c * CHR) * 3072 + e0;
    #pragma unroll 4
    for (int j = 0; j < CHR; ++j) {
      us4 wr = *(const us4*)(Wb + (long)j * 3072);
      us4 wz = *(const us4*)(Wb + (long)j * 3072 + 1024);
      us4 wn = *(const us4*)(Wb + (long)j * 3072 + 2048);
      float hv0 = h0s[j], hv1 = h1s[j];
      #pragma unroll
      for (int q = 0; q < 4; ++q) {
        float fr = b2f(wr[q]), fz = b2f(wz[q]), fn = b2f(wn[q]);
        ar0[q] += hv0 * fr; az0[q] += hv0 * fz; an0[q] += hv0 * fn;
        ar1[q] += hv1 * fr; az1[q] += hv1 * fz; an1[q] += hv1 * fn;
      }
    }
    long i0 = ((long)c * 64 + b0) * 1024 + e0;
    long i1 = i0 + 1024;
    *(float4*)(pRw + i0) = make_float4(ar0[0], ar0[1], ar0[2], ar0[3]);
    *(float4*)(pZw + i0) = make_float4(az0[0], az0[1], az0[2], az0[3]);
    *(float4*)(pNw + i0) = make_float4(an0[0], an0[1], an0[2], an0[3]);
    *(float4*)(pRw + i1) = make_float4(ar1[0], ar1[1], ar1[2], ar1[3]);
    *(float4*)(pZw + i1) = make_float4(az1[0], az1[1], az1[2], az1[3]);
    *(float4*)(pNw + i1) = make_float4(an1[0], an1[1], an1[2], an1[3]);
  }
}

// ---------- latent ----------
__global__ void latent_k(const float* __restrict__ h_enc,
                         const float* __restrict__ to_mu, const float* __restrict__ to_lsig,
                         const float* __restrict__ lsig_bias, const float* __restrict__ eps,
                         float* __restrict__ out_mu, float* __restrict__ out_lsig,
                         float* __restrict__ zlat) {
  int b = blockIdx.x;
  __shared__ float hs[1024];
  for (int i = threadIdx.x; i < 1024; i += blockDim.x) hs[i] = h_enc[b * 1024 + i];
  __syncthreads();
  int k = threadIdx.x;
  if (k < nK) {
    float am = 0.f, as = 0.f;
    for (int h = 0; h < 1024; ++h) { float hv = hs[h]; am += hv * to_mu[h * nK + k]; as += hv * to_lsig[h * nK + k]; }
    float ls = as + lsig_bias[k];
    out_mu[b * nK + k] = am;
    out_lsig[b * nK + k] = ls;
    zlat[b * nK + k] = am + eps[b * nK + k] * __expf(ls);
  }
}

// ---------- hypernet layers 1-2 ----------
__global__ __launch_bounds__(256) void hyper_k(const float* __restrict__ zlat,
                                               const float* __restrict__ W1, const float* __restrict__ b1,
                                               const float* __restrict__ W2, const float* __restrict__ b2,
                                               float* __restrict__ a2out) {
  int b = blockIdx.x;
  __shared__ float a1[1024];
  __shared__ float zv[nK];
  if (threadIdx.x < nK) zv[threadIdx.x] = zlat[b * nK + threadIdx.x];
  __syncthreads();
  for (int j = threadIdx.x; j < 1024; j += 256) {
    float acc = b1[j];
    #pragma unroll
    for (int i = 0; i < nK; ++i) acc += zv[i] * W1[i * 1024 + j];
    a1[j] = tanhf(acc);
  }
  __syncthreads();
  int l = threadIdx.x >> 3;
  int s = threadIdx.x & 7;
  if (l < 30) {
    float acc = 0.f;
    for (int j = s; j < 1024; j += 8) acc += a1[j] * W2[j * 30 + l];
    acc += __shfl_xor(acc, 4);
    acc += __shfl_xor(acc, 2);
    acc += __shfl_xor(acc, 1);
    if (s == 0) a2out[b * 30 + l] = acc + b2[l];
  }
}

// ---------- psi materialization ----------
__global__ __launch_bounds__(256) void psi_k(const float* __restrict__ a2,
                                             const float* __restrict__ W3, const float* __restrict__ b3,
                                             unsigned short* __restrict__ WhhB, float* __restrict__ Rest) {
  __shared__ float sa[64 * 30];
  for (int i = threadIdx.x; i < 64 * 30; i += 256) sa[i] = a2[i];
  long n = (long)blockIdx.x * 256 + threadIdx.x;
  __syncthreads();
  if (n >= N_PSI) return;
  float w[30];
  #pragma unroll
  for (int l = 0; l < 30; ++l) w[l] = W3[(long)l * N_PSI + n];
  float bb = b3[n];
  bool isWhh = (n < SZ_WHH);
  for (int b = 0; b < 64; ++b) {
    float acc = bb;
    const float* ab = &sa[b * 30];
    #pragma unroll
    for (int l = 0; l < 30; ++l) acc += ab[l] * w[l];
    if (isWhh) WhhB[(long)b * SZ_WHH + n] = f2b(acc);
    else       Rest[(long)b * REST_SZ + (n - SZ_WHH)] = acc;
  }
}

// ---------- decoder fused step ----------
__global__ __launch_bounds__(256) void dec_step_k(
    const unsigned short* __restrict__ WhhB,   // [B][1024][1024] bf16
    const unsigned short* __restrict__ gWhhB,  // [1024][2048] bf16
    const unsigned short* __restrict__ gxD,    // [T][B][2048] bf16 (incl gbias)
    const unsigned short* __restrict__ xWb,    // [T][B][1024] bf16
    const float* __restrict__ Rest,
    float* __restrict__ decS,                  // [B][T][1024]
    const float* __restrict__ pZr, const float* __restrict__ pRr, const float* __restrict__ pWr,
    float* __restrict__ pZw, float* __restrict__ pRw, float* __restrict__ pWw,
    int t) {
  int c = blockIdx.x & (NCH - 1);
  int sp = blockIdx.x >> 4;
  int b0 = sp * 2, b1 = b0 + 1;
  __shared__ float h0s[CHR], h1s[CHR];

  // phase A: reduce + gates -> h(t)
  int v = threadIdx.x;
  if (v < 2 * CHR) {
    int hi = v >> 6;
    int bb = hi ? b1 : b0;
    int k = c * CHR + (v & 63);
    float sz = 0.f, sr = 0.f, sw = 0.f;
    float hold = 0.f;
    if (t > 0) {
      #pragma unroll
      for (int cc = 0; cc < NCH; ++cc) {
        long base = ((long)cc * 64 + bb) * 1024 + k;
        sz += pZr[base]; sr += pRr[base]; sw += pWr[base];
      }
      hold = decS[((long)bb * nT + (t - 1)) * 1024 + k];
    }
    long gb = ((long)t * 64 + bb) * 2048;
    float gz = b2f(gxD[gb + k]), gr = b2f(gxD[gb + 1024 + k]);
    float z = sigm(gz + sz);
    float r = sigm(gr + sr);
    float hW = sw + Rest[(long)bb * REST_SZ + R_BH + k];
    float xw = b2f(xWb[((long)t * 64 + bb) * 1024 + k]);
    float eta = tanhf(xw + r * tanhf(hW));
    float hnew = z * hold + (1.f - z) * eta;
    decS[((long)bb * nT + t) * 1024 + k] = hnew;
    if (hi) h1s[v & 63] = hnew; else h0s[v & 63] = hnew;
  }
  __syncthreads();

  // phase B: partials for t+1
  if (t < nT - 1) {
    int k0 = threadIdx.x * 4;
    float az0[4] = {}, ar0[4] = {}, aw0[4] = {}, az1[4] = {}, ar1[4] = {}, aw1[4] = {};
    const unsigned short* G = gWhhB + (long)(c * CHR) * 2048 + k0;
    const unsigned short* W0 = WhhB + (long)b0 * SZ_WHH + (long)(c * CHR) * 1024 + k0;
    const unsigned short* W1p = WhhB + (long)b1 * SZ_WHH + (long)(c * CHR) * 1024 + k0;
    #pragma unroll 4
    for (int j = 0; j < CHR; ++j) {
      us4 wz = *(const us4*)(G + (long)j * 2048);
      us4 wr = *(const us4*)(G + (long)j * 2048 + 1024);
      us4 w0 = *(const us4*)(W0 + (long)j * 1024);
      us4 w1 = *(const us4*)(W1p + (long)j * 1024);
      float hv0 = h0s[j], hv1 = h1s[j];
      #pragma unroll
      for (int q = 0; q < 4; ++q) {
        float fz = b2f(wz[q]), fr = b2f(wr[q]), f0 = b2f(w0[q]), f1 = b2f(w1[q]);
        az0[q] += hv0 * fz; ar0[q] += hv0 * fr; aw0[q] += hv0 * f0;
        az1[q] += hv1 * fz; ar1[q] += hv1 * fr; aw1[q] += hv1 * f1;
      }
    }
    long i0 = ((long)c * 64 + b0) * 1024 + k0;
    long i1 = i0 + 1024;
    *(float4*)(pZw + i0) = make_float4(az0[0], az0[1], az0[2], az0[3]);
    *(float4*)(pRw + i0) = make_float4(ar0[0], ar0[1], ar0[2], ar0[3]);
    *(float4*)(pWw + i0) = make_float4(aw0[0], aw0[1], aw0[2], aw0[3]);
    *(float4*)(pZw + i1) = make_float4(az1[0], az1[1], az1[2], az1[3]);
    *(float4*)(pRw + i1) = make_float4(ar1[0], ar1[1], ar1[2], ar1[3]);
    *(float4*)(pWw + i1) = make_float4(aw1[0], aw1[1], aw1[2], aw1[3]);
  }
}

// ---------- readout: block = (sample, 8 timesteps), C stripe reused ----------
__global__ __launch_bounds__(256) void readout_k(
    const float* __restrict__ dec_seq, const float* __restrict__ inputs,
    const float* __restrict__ Rest, float* __restrict__ yhats) {
  int b = blockIdx.x >> 3;
  int tg = blockIdx.x & 7;             // 8 timesteps per block
  __shared__ float ss[8][1024];        // 32 KB
  __shared__ float part[4][8][64];     // 8 KB
  for (int i = threadIdx.x; i < 8 * 1024; i += 256)
    ss[i >> 10][i & 1023] = dec_seq[((long)b * nT + tg * 8 + (i >> 10)) * 1024 + (i & 1023)];
  __syncthreads();
  int m = threadIdx.x & 63, hq = threadIdx.x >> 6;
  const float* C = Rest + (long)b * REST_SZ + R_C;
  float acc[8] = {};
  for (int h = hq * 256; h < hq * 256 + 256; ++h) {
    float cv = C[(long)h * 64 + m];
    #pragma unroll
    for (int tt = 0; tt < 8; ++tt) acc[tt] += ss[tt][h] * cv;
  }
  #pragma unroll
  for (int tt = 0; tt < 8; ++tt) part[hq][tt][m] = acc[tt];
  __syncthreads();
  const float* D = Rest + (long)b * REST_SZ + R_D;
  for (int o = threadIdx.x; o < 512; o += 256) {
    int tt = o >> 6, mm = o & 63;
    float a = part[0][tt][mm] + part[1][tt][mm] + part[2][tt][mm] + part[3][tt][mm];
    long bt = (long)b * nT + tg * 8 + tt;
    if (mm < 8) {
      a += inputs[bt * 8 + mm];
    } else {
      #pragma unroll
      for (int i = 0; i < 8; ++i) a += inputs[bt * 8 + i] * D[i * 56 + (mm - 8)];
    }
    yhats[bt * 64 + mm] = a;
  }
}

__global__ void copy_states_k(const float* __restrict__ dec_seq, float* __restrict__ states) {
  int i = blockIdx.x * 256 + threadIdx.x;
  int b = i >> 10, h = i & 1023;
  states[i] = dec_seq[((long)b * nT + (nT - 1)) * 1024 + h];
}

extern "C" void kernel_launch(void* const* d_in, const int* in_sizes, int n_in,
                              void* d_out, int out_size, void* d_ws, size_t ws_size,
                              hipStream_t stream) {
  const float* inputs  = (const float*)d_in[0];
  const float* outputs = (const float*)d_in[1];
  const float* eps     = (const float*)d_in[2];
  const float* enc_Wih = (const float*)d_in[3];
  const float* enc_Whh = (const float*)d_in[4];
  const float* enc_bih = (const float*)d_in[5];
  const float* enc_bhh = (const float*)d_in[6];
  const float* to_mu   = (const float*)d_in[7];
  const float* to_lsig = (const float*)d_in[8];
  const float* lsig_b  = (const float*)d_in[9];
  const float* W1 = (const float*)d_in[10];
  const float* b1 = (const float*)d_in[11];
  const float* W2 = (const float*)d_in[12];
  const float* b2 = (const float*)d_in[13];
  const float* W3 = (const float*)d_in[14];
  const float* b3 = (const float*)d_in[15];
  const float* gWih  = (const float*)d_in[16];
  const float* gWhh  = (const float*)d_in[17];
  const float* gbias = (const float*)d_in[18];

  char* ws = (char*)d_ws;
  size_t off = 0;
  auto alloc = [&](size_t bytes) { size_t o = off; off = (off + bytes + 255) & ~(size_t)255; return o; };
  size_t oWhhB   = alloc(64ull * SZ_WHH * 2);        // bf16 per-sample Whh
  size_t oRest   = alloc(64ull * REST_SZ * 4);       // fp32 psi remainder
  size_t ogWhhB  = alloc(1024ull * 2048 * 2);        // bf16 gru_Whh
  size_t oWtWhhB = alloc(1024ull * 3072 * 2);        // bf16 enc_Whh^T
  size_t oWtWihB = alloc(64ull * 3072 * 2);          // bf16 enc_Wih^T
  size_t ogxE    = alloc(64ull * 64 * 3072 * 2);     // bf16 encoder gx (incl bih)
  size_t ogxD    = alloc(64ull * 64 * 2048 * 2);     // bf16 decoder gx (incl gbias)
  size_t oxWb    = alloc(64ull * 64 * 1024 * 2);     // bf16 x@Wih_b
  size_t opA     = alloc((size_t)2 * PHALF * 4);     // double-buffered partials
  size_t opB     = alloc((size_t)2 * PHALF * 4);
  size_t opC     = alloc((size_t)2 * PHALF * 4);
  size_t ohA     = alloc(64ull * 1024 * 4);          // encoder h (running)
  size_t oDec    = alloc(64ull * 64 * 1024 * 4);
  size_t oZ      = alloc(64 * nK * 4);
  size_t oA2     = alloc(64 * 30 * 4);
  (void)ws_size; (void)in_sizes; (void)n_in; (void)out_size;

  unsigned short* WhhB   = (unsigned short*)(ws + oWhhB);
  float*          Rest   = (float*)(ws + oRest);
  unsigned short* gWhhB  = (unsigned short*)(ws + ogWhhB);
  unsigned short* WtWhhB = (unsigned short*)(ws + oWtWhhB);
  unsigned short* WtWihB = (unsigned short*)(ws + oWtWihB);
  unsigned short* gxE    = (unsigned short*)(ws + ogxE);
  unsigned short* gxD    = (unsigned short*)(ws + ogxD);
  unsigned short* xWb    = (unsigned short*)(ws + oxWb);
  float* pA   = (float*)(ws + opA);
  float* pB   = (float*)(ws + opB);
  float* pC   = (float*)(ws + opC);
  float* hA   = (float*)(ws + ohA);
  float* decS = (float*)(ws + oDec);
  float* zlat = (float*)(ws + oZ);
  float* a2   = (float*)(ws + oA2);

  float* out    = (float*)d_out;
  float* out_yh = out;                 // 262144
  float* out_mu = out + 262144;        // 448
  float* out_ls = out + 262144 + 448;  // 448
  float* out_st = out + 262144 + 896;  // 65536

  // 1) weight preprocessing (bf16)
  transpose_bf16_k<<<dim3(32, 96), dim3(32, 8), 0, stream>>>(enc_Whh, WtWhhB, 3072, 1024);
  transpose_bf16_k<<<dim3(2, 96),  dim3(32, 8), 0, stream>>>(enc_Wih, WtWihB, 3072, 64);
  cvt_bf16_k<<<(int)((1024ull * 2048 + 255) / 256), 256, 0, stream>>>(gWhh, gWhhB, 1024 * 2048);

  // 2) bulk encoder gx
  enc_gx_k<<<dim3(12, 64), 256, 0, stream>>>(outputs, WtWihB, enc_bih, gxE);

  // 3) encoder recurrence: one fused kernel per step
  for (int t = 0; t < nT; ++t) {
    int rp = t & 1, wp = (t + 1) & 1;
    enc_step_k<<<512, 256, 0, stream>>>(WtWhhB, gxE, enc_bhh, hA,
        pA + (size_t)rp * PHALF, pB + (size_t)rp * PHALF, pC + (size_t)rp * PHALF,
        pA + (size_t)wp * PHALF, pB + (size_t)wp * PHALF, pC + (size_t)wp * PHALF, t);
  }

  // 4) latent + hypernet + psi
  latent_k<<<64, 64, 0, stream>>>(hA, to_mu, to_lsig, lsig_b, eps, out_mu, out_ls, zlat);
  hyper_k<<<64, 256, 0, stream>>>(zlat, W1, b1, W2, b2, a2);
  psi_k<<<(int)((N_PSI + 255) / 256), 256, 0, stream>>>(a2, W3, b3, WhhB, Rest);

  // 5) bulk decoder gx and x@Wih_b
  dec_gx_k<<<dim3(8, 64), 256, 0, stream>>>(inputs, gWih, gbias, gxD);
  xW_k<<<dim3(4, 64), 256, 0, stream>>>(inputs, Rest, xWb);

  // 6) decoder recurrence: one fused kernel per step
  for (int t = 0; t < nT; ++t) {
    int rp = t & 1, wp = (t + 1) & 1;
    dec_step_k<<<512, 256, 0, stream>>>(WhhB, gWhhB, gxD, xWb, Rest, decS,
        pA + (size_t)rp * PHALF, pB + (size_t)rp * PHALF, pC + (size_t)rp * PHALF,
        pA + (size_t)wp * PHALF, pB + (size_t)wp * PHALF, pC + (size_t)wp * PHALF, t);
  }

  // 7) readout + states
  readout_k<<<512, 256, 0, stream>>>(decS, inputs, Rest, out_yh);
  copy_states_k<<<256, 256, 0, stream>>>(decS, out_st);
}